// Round 1
// baseline (683.573 us; speedup 1.0000x reference)
//
#include <hip/hip_runtime.h>
#include <math.h>

#define DIM 16        // 2^Q, Q=4
#define BATCH 2       // B from setup_inputs
#define TT 16         // tokens per block in projection kernel

// ---------------------------------------------------------------------------
// Kernel A: embedding gather + normalize + noisy circuit + mask select.
// One thread per token (B*S = 4096 threads). Writes processed [B*S, 16] to ws.
// ---------------------------------------------------------------------------
__global__ void quantum_state_kernel(const int* __restrict__ ids,
                                     const int* __restrict__ mask,
                                     const float* __restrict__ W_embed,
                                     const float* __restrict__ gates,
                                     float* __restrict__ proc,
                                     int B, int S, int depth) {
    extern __shared__ float g[];                 // depth*DIM*DIM gate coeffs
    const int tid = threadIdx.x;
    const int ng = depth * DIM * DIM;
    for (int i = tid; i < ng; i += blockDim.x) g[i] = gates[i];
    __syncthreads();

    const int t = blockIdx.x * blockDim.x + tid; // token index b*S + s
    const int total = B * S;
    if (t >= total) return;
    const int s_idx = t % S;

    // embedding lookup + normalize: emb = row / (||row|| + 1e-12)
    const int id = ids[t];
    const float* row = W_embed + (long)id * DIM;
    float e[DIM];
    float ss = 0.f;
#pragma unroll
    for (int k = 0; k < DIM; ++k) { e[k] = row[k]; ss += e[k] * e[k]; }
    float inv = 1.0f / (sqrtf(ss) + 1e-12f);
#pragma unroll
    for (int k = 0; k < DIM; ++k) e[k] *= inv;

    // noisy circuit
    float st[DIM];
#pragma unroll
    for (int k = 0; k < DIM; ++k) st[k] = e[k];
    for (int l = 0; l < depth; ++l) {
        const float* gl = g + l * DIM * DIM;
        float ns[DIM];
#pragma unroll
        for (int ei = 0; ei < DIM; ++ei) {
            float acc = 0.f;
#pragma unroll
            for (int d = 0; d < DIM; ++d) acc += gl[ei * DIM + d] * st[d];
            ns[ei] = acc;
        }
        ss = 0.f;
#pragma unroll
        for (int k = 0; k < DIM; ++k) {
            float v = ns[k] * 0.99f;              // decoherence (1-0.01)
            v = 0.99f * v + 0.000625f;            // depolarization 0.99*x + 0.01/16
            ns[k] = v;
            ss += v * v;
        }
        inv = 1.0f / (sqrtf(ss) + 1e-12f);
#pragma unroll
        for (int k = 0; k < DIM; ++k) st[k] = ns[k] * inv;
    }
#pragma unroll
    for (int k = 0; k < DIM; ++k) st[k] = 0.99f * st[k] + 0.000625f;  // measurement error

    // apply only if mask[:, s] all nonzero
    bool apply = true;
    for (int b = 0; b < B; ++b) apply = apply && (mask[b * S + s_idx] != 0);

#pragma unroll
    for (int k = 0; k < DIM; ++k) proc[(long)t * DIM + k] = apply ? st[k] : e[k];
}

// ---------------------------------------------------------------------------
// Kernel B: out[t, v] = dot(proc[t,:], W_out[v,:]) + b_out[v]
// Block = 256 threads handles TT=16 tokens x 1024 vocab entries.
// Each thread owns 4 consecutive vocab rows (64 VGPRs of W_out) and emits
// coalesced float4 stores. Token states broadcast from LDS.
// ---------------------------------------------------------------------------
__global__ __launch_bounds__(256) void out_proj_kernel(
        const float* __restrict__ proc,
        const float* __restrict__ W_out,
        const float* __restrict__ b_out,
        float* __restrict__ out,
        int V, int total_tokens) {
    __shared__ float sstate[TT][DIM];
    const int tid = threadIdx.x;
    const int t0 = blockIdx.x * TT;

    // 256 threads load exactly TT*DIM = 256 floats
    {
        int idx = tid;
        int tok = idx / DIM, k = idx % DIM;
        int t = t0 + tok;
        sstate[tok][k] = (t < total_tokens) ? proc[(long)t * DIM + k] : 0.f;
    }
    __syncthreads();

    const int v0 = blockIdx.y * 1024 + tid * 4;
    if (v0 >= V) return;
    const int nv = min(4, V - v0);

    float w[4][DIM];
    float bias[4];
    for (int j = 0; j < nv; ++j) {
        const float4* wr = (const float4*)(W_out + (long)(v0 + j) * DIM);
        float4 a = wr[0], b4 = wr[1], c = wr[2], d = wr[3];
        w[j][0] = a.x;  w[j][1] = a.y;  w[j][2] = a.z;  w[j][3] = a.w;
        w[j][4] = b4.x; w[j][5] = b4.y; w[j][6] = b4.z; w[j][7] = b4.w;
        w[j][8] = c.x;  w[j][9] = c.y;  w[j][10] = c.z; w[j][11] = c.w;
        w[j][12] = d.x; w[j][13] = d.y; w[j][14] = d.z; w[j][15] = d.w;
        bias[j] = b_out[v0 + j];
    }

    for (int tk = 0; tk < TT; ++tk) {
        const int t = t0 + tk;
        if (t >= total_tokens) break;
        float acc0 = bias[0], acc1 = bias[1], acc2 = bias[2], acc3 = bias[3];
#pragma unroll
        for (int k = 0; k < DIM; ++k) {
            const float sv = sstate[tk][k];  // wave-uniform address -> LDS broadcast
            acc0 += sv * w[0][k];
            acc1 += sv * w[1][k];
            acc2 += sv * w[2][k];
            acc3 += sv * w[3][k];
        }
        const long o = (long)t * V + v0;
        if (nv == 4) {
            *(float4*)(out + o) = make_float4(acc0, acc1, acc2, acc3);
        } else {
            float accs[4] = {acc0, acc1, acc2, acc3};
            for (int j = 0; j < nv; ++j) out[o + j] = accs[j];
        }
    }
}

extern "C" void kernel_launch(void* const* d_in, const int* in_sizes, int n_in,
                              void* d_out, int out_size, void* d_ws, size_t ws_size,
                              hipStream_t stream) {
    const int*   ids    = (const int*)  d_in[0];  // [B,S]
    const int*   mask   = (const int*)  d_in[1];  // [B,S]
    const float* W_emb  = (const float*)d_in[2];  // [V,16]
    const float* gates  = (const float*)d_in[3];  // [depth,16,16]
    const float* W_out  = (const float*)d_in[4];  // [V,16]
    const float* b_out  = (const float*)d_in[5];  // [V]
    float* out = (float*)d_out;

    const int B = BATCH;
    const int total = in_sizes[0];          // B*S
    const int S = total / B;
    const int V = in_sizes[5];
    const int depth = in_sizes[3] / (DIM * DIM);

    float* proc = (float*)d_ws;             // [total, DIM] scratch (256 KB)

    // Kernel A: tiny — compute processed states
    {
        dim3 block(256);
        dim3 grid((total + 255) / 256);
        size_t shmem = (size_t)depth * DIM * DIM * sizeof(float);
        quantum_state_kernel<<<grid, block, shmem, stream>>>(
            ids, mask, W_emb, gates, proc, B, S, depth);
    }

    // Kernel B: projection, write-bound
    {
        dim3 block(256);
        dim3 grid((total + TT - 1) / TT, (V + 1023) / 1024);
        out_proj_kernel<<<grid, block, 0, stream>>>(proc, W_out, b_out, out, V, total);
    }
}